// Round 1
// baseline (82.864 us; speedup 1.0000x reference)
//
#include <hip/hip_runtime.h>

#define LEAKY_S 0.01f
#define BN_EPS 1e-5f

__device__ __forceinline__ float leaky(float v) { return v >= 0.0f ? v : LEAKY_S * v; }

// ---------------- K1: partial sums (sum, sumsq) of h1 columns over batch ----
__global__ __launch_bounds__(256) void k_part1(const float* __restrict__ x,
        const float* __restrict__ w1, const float* __restrict__ b1,
        float* __restrict__ p1, int B) {
    float w1r[16], b1r[16], s[16], q[16];
#pragma unroll
    for (int j = 0; j < 16; ++j) { w1r[j] = w1[j]; b1r[j] = b1[j]; s[j] = 0.f; q[j] = 0.f; }
    int tid = threadIdx.x;
    int stride = gridDim.x * 256;
    for (int i = blockIdx.x * 256 + tid; i < B; i += stride) {
        float xv = x[i];
#pragma unroll
        for (int j = 0; j < 16; ++j) {
            float h = leaky(fmaf(xv, w1r[j], b1r[j]));
            s[j] += h; q[j] += h * h;
        }
    }
#pragma unroll
    for (int j = 0; j < 16; ++j) {
        for (int off = 32; off >= 1; off >>= 1) {
            s[j] += __shfl_xor(s[j], off, 64);
            q[j] += __shfl_xor(q[j], off, 64);
        }
    }
    __shared__ float red[4][32];
    int w = tid >> 6, lane = tid & 63;
    if (lane == 0) {
#pragma unroll
        for (int j = 0; j < 16; ++j) { red[w][j] = s[j]; red[w][j + 16] = q[j]; }
    }
    __syncthreads();
    if (tid < 32)
        p1[blockIdx.x * 32 + tid] = red[0][tid] + red[1][tid] + red[2][tid] + red[3][tid];
}

// ------- K2: finalize BN1 + fold Linear2: a[j] = invstd1*g1*w2, c0 = bias ---
__global__ void k_fin1(const float* __restrict__ p1, const float* __restrict__ w2,
        const float* __restrict__ b2, const float* __restrict__ g1,
        const float* __restrict__ be1, float* __restrict__ st1, int nblk, float invB) {
    int tid = threadIdx.x;
    __shared__ float sred[32];
    __shared__ float cpart[16];
    if (tid < 32) {
        float acc = 0.f;
        for (int i = 0; i < nblk; ++i) acc += p1[i * 32 + tid];
        sred[tid] = acc;
    }
    __syncthreads();
    if (tid < 16) {
        float mean = sred[tid] * invB;
        float var  = sred[tid + 16] * invB - mean * mean;
        float inv  = rsqrtf(var + BN_EPS) * g1[tid];
        float sh   = fmaf(-mean, inv, be1[tid]);
        st1[tid]   = inv * w2[tid];
        cpart[tid] = sh * w2[tid];
    }
    __syncthreads();
    if (tid == 0) {
        float c0 = b2[0];
        for (int j = 0; j < 16; ++j) c0 += cpart[j];
        st1[16] = c0;
    }
}

// ---------------- K3: h2 per row, partial (sum, sumsq) for BN2 --------------
__global__ __launch_bounds__(256) void k_h2(const float* __restrict__ x,
        const float* __restrict__ w1, const float* __restrict__ b1,
        const float* __restrict__ st1, float* __restrict__ p2, int B) {
    float w1r[16], b1r[16], ar[16];
#pragma unroll
    for (int j = 0; j < 16; ++j) { w1r[j] = w1[j]; b1r[j] = b1[j]; ar[j] = st1[j]; }
    float c0 = st1[16];
    float s = 0.f, q = 0.f;
    int tid = threadIdx.x;
    int stride = gridDim.x * 256;
    for (int i = blockIdx.x * 256 + tid; i < B; i += stride) {
        float xv = x[i];
        float acc = c0;
#pragma unroll
        for (int j = 0; j < 16; ++j) {
            float h = leaky(fmaf(xv, w1r[j], b1r[j]));
            acc = fmaf(h, ar[j], acc);
        }
        float h2 = leaky(acc);
        s += h2; q += h2 * h2;
    }
    for (int off = 32; off >= 1; off >>= 1) {
        s += __shfl_xor(s, off, 64);
        q += __shfl_xor(q, off, 64);
    }
    __shared__ float red[4][2];
    int w = tid >> 6, lane = tid & 63;
    if (lane == 0) { red[w][0] = s; red[w][1] = q; }
    __syncthreads();
    if (tid == 0) {
        p2[blockIdx.x * 2 + 0] = red[0][0] + red[1][0] + red[2][0] + red[3][0];
        p2[blockIdx.x * 2 + 1] = red[0][1] + red[1][1] + red[2][1] + red[3][1];
    }
}

// ---------------- K4: finalize BN2 -> s2 (scale), t2 (shift) ----------------
__global__ void k_fin2(const float* __restrict__ p2, const float* __restrict__ g2,
        const float* __restrict__ be2, float* __restrict__ st2, int nblk, float invB) {
    int tid = threadIdx.x;
    float s = 0.f, q = 0.f;
    if (tid < nblk) { s = p2[tid * 2]; q = p2[tid * 2 + 1]; }
    for (int off = 32; off >= 1; off >>= 1) {
        s += __shfl_xor(s, off, 64);
        q += __shfl_xor(q, off, 64);
    }
    if (tid == 0) {
        float mean = s * invB;
        float var  = q * invB - mean * mean;
        float inv  = rsqrtf(var + BN_EPS) * g2[0];
        st2[0] = inv;
        st2[1] = fmaf(-mean, inv, be2[0]);
    }
}

// ---------------- K5: main tree kernel. One wave per row. -------------------
// mu heap recurrence: mu[1]=1; for parent n: mu[2n]=mu[n]*p[n], mu[2n+1]=mu[n]-mu[2n]
// p[n] = sigmoid(x2*fcw[n] + fcb[n]).  Children stored to LDS (next level's
// parents, levels 1..9) and streamed to global as coalesced float2.
__global__ __launch_bounds__(256) void k_tree(const float* __restrict__ x,
        const float* __restrict__ w1, const float* __restrict__ b1,
        const float* __restrict__ st1, const float* __restrict__ fcw,
        const float* __restrict__ fcb, const float* __restrict__ st2,
        float* __restrict__ out, int B, int iters) {
    __shared__ float wl[1024];
    __shared__ float bl[1024];
    __shared__ float mu[4][1024];
    int tid = threadIdx.x;
    for (int i = tid; i < 1024; i += 256) { wl[i] = fcw[i]; bl[i] = fcb[i]; }

    float w1r[16], b1r[16], ar[16];
#pragma unroll
    for (int j = 0; j < 16; ++j) { w1r[j] = w1[j]; b1r[j] = b1[j]; ar[j] = st1[j]; }
    float c0 = st1[16];
    float s2 = st2[0], t2 = st2[1];

    int w = tid >> 6, lane = tid & 63;
    int waveId = blockIdx.x * 4 + w;
    int nwaves = gridDim.x * 4;
    __syncthreads();

    for (int it = 0; it < iters; ++it) {
        int r = waveId + it * nwaves;
        bool act = (r < B);   // wave-uniform
        float x2 = 0.f;
        float* orow = out;
        if (act) {
            // recompute h2 from x (cheap, wave-redundant), apply BN2
            float xv = x[r];
            float acc = c0;
#pragma unroll
            for (int j = 0; j < 16; ++j) {
                float h = leaky(fmaf(xv, w1r[j], b1r[j]));
                acc = fmaf(h, ar[j], acc);
            }
            x2 = fmaf(leaky(acc), s2, t2);
            orow = out + (size_t)r * 2048;
            if (lane == 0) { orow[0] = 0.f; orow[1] = 1.f; mu[w][1] = 1.f; }
        }
        for (int l = 1; l <= 10; ++l) {
            __syncthreads();   // block-uniform: orders LDS mu writes vs reads
            if (act) {
                int P = 1 << (l - 1);          // parents this level
                for (int i = lane; i < P; i += 64) {
                    int n = P + i;             // parent heap index
                    float mup = mu[w][n];
                    float z = fmaf(x2, wl[n], bl[n]);
                    float pz = 1.0f / (1.0f + __expf(-z));
                    float cc0 = mup * pz;
                    float cc1 = mup - cc0;
                    if (l < 10)
                        *reinterpret_cast<float2*>(&mu[w][2 * n]) = make_float2(cc0, cc1);
                    *reinterpret_cast<float2*>(orow + 2 * n) = make_float2(cc0, cc1);
                }
            }
        }
    }
}

extern "C" void kernel_launch(void* const* d_in, const int* in_sizes, int n_in,
                              void* d_out, int out_size, void* d_ws, size_t ws_size,
                              hipStream_t stream) {
    const float* x   = (const float*)d_in[0];
    const float* w1  = (const float*)d_in[1];
    const float* b1  = (const float*)d_in[2];
    const float* g1  = (const float*)d_in[3];
    const float* be1 = (const float*)d_in[4];
    const float* w2  = (const float*)d_in[5];
    const float* b2  = (const float*)d_in[6];
    const float* g2  = (const float*)d_in[7];
    const float* be2 = (const float*)d_in[8];
    const float* fcw = (const float*)d_in[9];
    const float* fcb = (const float*)d_in[10];
    float* out = (float*)d_out;
    int B = in_sizes[0];
    float invB = 1.0f / (float)B;

    float* ws  = (float*)d_ws;
    float* p1  = ws;          // 64*32 partials for BN1
    float* st1 = ws + 2048;   // a[16], c0
    float* p2  = ws + 2176;   // 64*2 partials for BN2
    float* st2 = ws + 2432;   // s2, t2

    const int RB = 64;
    k_part1<<<RB, 256, 0, stream>>>(x, w1, b1, p1, B);
    k_fin1 <<<1, 64, 0, stream>>>(p1, w2, b2, g1, be1, st1, RB, invB);
    k_h2   <<<RB, 256, 0, stream>>>(x, w1, b1, st1, p2, B);
    k_fin2 <<<1, 64, 0, stream>>>(p2, g2, be2, st2, RB, invB);

    int blocks = 2048;                      // 8192 waves, 4 rows per wave
    int nwaves = blocks * 4;
    int iters = (B + nwaves - 1) / nwaves;  // uniform trip count (barrier safety)
    k_tree<<<blocks, 256, 0, stream>>>(x, w1, b1, st1, fcw, fcb, st2, out, B, iters);
}